// Round 17
// baseline (772.404 us; speedup 1.0000x reference)
//
#include <hip/hip_runtime.h>
#include <hip/hip_bf16.h>

#define N_NODES 50000
#define N_EDGES 800000
#define DIM     128
#define DIM2    256
#define NLAYER  5
#define NGRAPH  512
#define TDIM    10
#define VMAX    119
#define ROWGRPS 782            // 782 row-groups x 64 rows = 50048 >= 50000
#define CSR_PASSES 4

typedef _Float16 f16x8 __attribute__((ext_vector_type(8)));
typedef _Float16 f16x2 __attribute__((ext_vector_type(2)));
typedef float    f32x4 __attribute__((ext_vector_type(4)));

// async global->LDS DMA; no dest VGPR so the scheduler CANNOT sink it.
static __device__ inline void dma16(void* lds, const void* g) {
#if defined(__has_builtin) && __has_builtin(__builtin_amdgcn_global_load_lds)
    __builtin_amdgcn_global_load_lds(
        (const __attribute__((address_space(1))) unsigned int*)g,
        (__attribute__((address_space(3))) unsigned int*)lds,
        16, 0, 0);
#else
    *(f16x8*)lds = *(const f16x8*)g;   // sync fallback, same layout
#endif
}

// 4 B/lane variant: one DMA moves 64 lanes x 4 B = 256 B = one full f16 row (DIM=128)
static __device__ inline void dma4(void* lds, const void* g) {
#if defined(__has_builtin) && __has_builtin(__builtin_amdgcn_global_load_lds)
    __builtin_amdgcn_global_load_lds(
        (const __attribute__((address_space(1))) unsigned int*)g,
        (__attribute__((address_space(3))) unsigned int*)lds,
        4, 0, 0);
#else
    *(unsigned int*)lds = *(const unsigned int*)g;
#endif
}

static __device__ inline void wait_vm() {
#if defined(__has_builtin) && __has_builtin(__builtin_amdgcn_s_waitcnt)
    __builtin_amdgcn_s_waitcnt(0);   // wave-level: drain vm/lgkm/exp
#else
    __threadfence_block();
#endif
}

static __device__ inline f16x8 relu8(f16x8 v) {
#if __has_builtin(__builtin_elementwise_max)
    return __builtin_elementwise_max(v, (f16x8){0, 0, 0, 0, 0, 0, 0, 0});
#else
    #pragma unroll
    for (int j = 0; j < 8; ++j) v[j] = v[j] > (_Float16)0 ? v[j] : (_Float16)0;
    return v;
#endif
}

static __device__ inline f16x2 relu2(f16x2 v) {
#if __has_builtin(__builtin_elementwise_max)
    return __builtin_elementwise_max(v, (f16x2){0, 0});
#else
    #pragma unroll
    for (int j = 0; j < 2; ++j) v[j] = v[j] > (_Float16)0 ? v[j] : (_Float16)0;
    return v;
#endif
}

// ---------------- weight convert + transpose to f16 [n][k] ----------------
__global__ void convert_w(const float* __restrict__ W1, const float* __restrict__ W2,
                          _Float16* __restrict__ W1t, _Float16* __restrict__ W2t) {
    int idx = blockIdx.x * 256 + threadIdx.x;
    if (idx >= NLAYER * DIM * DIM2) return;
    int l = idx / (DIM * DIM2);
    int rem = idx % (DIM * DIM2);
    int k1 = rem / DIM2, n1 = rem % DIM2;
    W1t[(size_t)l * DIM * DIM2 + (size_t)n1 * DIM + k1] = (_Float16)W1[idx];
    int k2 = rem / DIM, n2 = rem % DIM;
    W2t[(size_t)l * DIM * DIM2 + (size_t)n2 * DIM2 + k2] = (_Float16)W2[idx];
}

// ---------------- atom encoder -> hraw f16 (GEMM1 layer0 A), hrel f16 (layer0 gather) ---
__global__ void atom_encoder(const int* __restrict__ x, const float* __restrict__ emb,
                             _Float16* __restrict__ hraw, _Float16* __restrict__ hrelu) {
    int node = blockIdx.x * 4 + (threadIdx.x >> 6);
    int lane = threadIdx.x & 63;
    if (node >= N_NODES) return;
    float2 acc = {0.f, 0.f};
    const int* xr = x + node * 9;
    #pragma unroll
    for (int t = 0; t < 9; ++t) {
        int v = xr[t];
        const float2* row = (const float2*)(emb + ((size_t)t * VMAX + v) * DIM);
        float2 e = row[lane];
        acc.x += e.x; acc.y += e.y;
    }
    f16x2 o, orl;
    o[0] = (_Float16)acc.x; o[1] = (_Float16)acc.y;
    orl[0] = (_Float16)fmaxf(acc.x, 0.f); orl[1] = (_Float16)fmaxf(acc.y, 0.f);
    ((f16x2*)(hraw + (size_t)node * DIM))[lane] = o;
    ((f16x2*)(hrelu + (size_t)node * DIM))[lane] = orl;
}

// ---------------- CSR build ----------------
__global__ void count_deg(const int* __restrict__ dst, int* __restrict__ deg) {
    int e = blockIdx.x * blockDim.x + threadIdx.x;
    if (e < N_EDGES) atomicAdd(&deg[dst[e]], 1);
}

__global__ void scan_a(const int* __restrict__ deg, int* __restrict__ rp, int* __restrict__ bsum) {
    __shared__ int s[512];
    int i = blockIdx.x * 512 + threadIdx.x;
    int v = (i < N_NODES) ? deg[i] : 0;
    s[threadIdx.x] = v;
    __syncthreads();
    for (int off = 1; off < 512; off <<= 1) {
        int t = (threadIdx.x >= off) ? s[threadIdx.x - off] : 0;
        __syncthreads();
        s[threadIdx.x] += t;
        __syncthreads();
    }
    if (i < N_NODES) rp[i] = s[threadIdx.x] - v;   // exclusive
    if (threadIdx.x == 511) bsum[blockIdx.x] = s[511];
}

__global__ void scan_b(const int* __restrict__ bsum, int* __restrict__ boff) {
    __shared__ int s[128];
    const int NB = 98;
    int v = (threadIdx.x < NB) ? bsum[threadIdx.x] : 0;
    s[threadIdx.x] = v;
    __syncthreads();
    for (int off = 1; off < 128; off <<= 1) {
        int t = (threadIdx.x >= off) ? s[threadIdx.x - off] : 0;
        __syncthreads();
        s[threadIdx.x] += t;
        __syncthreads();
    }
    if (threadIdx.x < NB) boff[threadIdx.x] = s[threadIdx.x] - v;
}

__global__ void scan_c(int* __restrict__ rp, const int* __restrict__ boff) {
    int i = blockIdx.x * 512 + threadIdx.x;
    if (i < N_NODES) rp[i] += boff[blockIdx.x];
    if (blockIdx.x == 0 && threadIdx.x == 0) rp[N_NODES] = N_EDGES;
}

// fill CSR for one dst range (L2-resident col footprint per pass -> write-combining).
__global__ void fill_csr_range(const int* __restrict__ src, const int* __restrict__ dst,
                               const int* __restrict__ rp, int* __restrict__ cursor,
                               int* __restrict__ col, int lo, int hi) {
    int e = blockIdx.x * blockDim.x + threadIdx.x;
    if (e >= N_EDGES) return;
    int d = dst[e];
    if (d < lo || d >= hi) return;
    int pos = atomicSub(&cursor[d], 1) - 1;
    col[rp[d] + pos] = src[e];
}

// -------- aggregation via un-sinkable row DMAs --------------------------------------
// 1 wave per node. Per 16-edge chunk: 16 size-4 DMAs (each = one full 256 B f16 row
// into a private LDS slot; 16 rows FORCED in flight — register-load versions let the
// scheduler sink to ~2), one wave-level waitcnt, 16 conflict-free ds_read_b32 +
// accumulate. 8-tier + direct tail for degree variance. No block barriers.
template <int APPLY_BN>
__global__ void gather_agg(const _Float16* __restrict__ hsrc, const int* __restrict__ rp,
                           const int* __restrict__ col, const _Float16* __restrict__ scale16,
                           const _Float16* __restrict__ shift16, _Float16* __restrict__ agg) {
    __shared__ __align__(16) char glds[4 * 16 * 256];   // 4 waves x 16 slots x 256 B
    int wave = threadIdx.x >> 6;
    int lane = threadIdx.x & 63;
    int node = blockIdx.x * 4 + wave;
    if (node >= N_NODES) return;
    char* slot = glds + wave * 4096;
    const char* hb = (const char*)hsrc;
    f16x2 sc = {0, 0}, sh = {0, 0};
    if (APPLY_BN) {
        sc = ((const f16x2*)scale16)[lane];
        sh = ((const f16x2*)shift16)[lane];
    }
    int e0 = rp[node], e1 = rp[node + 1];
    float2 acc = {0.f, 0.f};
    int e = e0;
    for (; e + 16 <= e1; e += 16) {
        int idxs[16];
        #pragma unroll
        for (int j = 0; j < 16; ++j) idxs[j] = col[e + j];
        #pragma unroll
        for (int j = 0; j < 16; ++j)
            dma4(slot + j * 256 + lane * 4, hb + (size_t)idxs[j] * 256 + (size_t)lane * 4);
        wait_vm();
        #pragma unroll
        for (int j = 0; j < 16; ++j) {
            f16x2 w = *(const f16x2*)(slot + j * 256 + lane * 4);
            if (APPLY_BN) w = relu2(w * sc + sh);
            acc.x += (float)w[0]; acc.y += (float)w[1];
        }
    }
    for (; e + 8 <= e1; e += 8) {
        int idxs[8];
        #pragma unroll
        for (int j = 0; j < 8; ++j) idxs[j] = col[e + j];
        #pragma unroll
        for (int j = 0; j < 8; ++j)
            dma4(slot + j * 256 + lane * 4, hb + (size_t)idxs[j] * 256 + (size_t)lane * 4);
        wait_vm();
        #pragma unroll
        for (int j = 0; j < 8; ++j) {
            f16x2 w = *(const f16x2*)(slot + j * 256 + lane * 4);
            if (APPLY_BN) w = relu2(w * sc + sh);
            acc.x += (float)w[0]; acc.y += (float)w[1];
        }
    }
    for (; e < e1; ++e) {
        f16x2 w = ((const f16x2*)(hsrc + (size_t)col[e] * DIM))[lane];
        if (APPLY_BN) w = relu2(w * sc + sh);
        acc.x += (float)w[0]; acc.y += (float)w[1];
    }
    f16x2 o;
    o[0] = (_Float16)acc.x; o[1] = (_Float16)acc.y;
    ((f16x2*)(agg + (size_t)node * DIM))[lane] = o;
}

// ---------------- MFMA GEMM: DMA-staged, A staged ONCE + both column halves -----------
// (round-16 proven) Grid = ROWGRPS; block = 64 rows x all NC cols in two half-phases.
// 64 LDS slots x 1 KB: 0..31 = B-half frags, 32..63 = A frags. A-frags built once in
// registers and reused across halves. Stats via LDS combine, no atomics.
// MODE 0: A[m][k] = (1+eps) * f(A0[m][k]) + A1[m][k], f = relu(x*sc+sh) if APPLY_BN
// MODE 1: A[m][k] = relu(A0[m][k]*sc[k] + sh[k])
template <int K, int NC, int MODE, int APPLY_BN, int STATS>
__global__ __launch_bounds__(256, 2) void gemm_mfma(
    const _Float16* __restrict__ A0h, const _Float16* __restrict__ A1h,
    const _Float16* __restrict__ Bt, const float* __restrict__ bias,
    const _Float16* __restrict__ scale16, const _Float16* __restrict__ shift16,
    const float* __restrict__ epsArr, int layer, _Float16* __restrict__ Cout,
    float* __restrict__ psum, float* __restrict__ psq) {
    const int HC = NC / 2;        // cols per half (128 or 64)
    const int NT = HC / 16;       // n-tiles per half (8 or 4)
    const int KI = K / 32;        // k-steps (4 or 8)
    const int BSLOTS = NT * KI;   // 32 for both shapes
    __shared__ __align__(16) char lds[65536];   // 64 slots x 1 KB

    int tid = threadIdx.x;
    int wave = tid >> 6, lane = tid & 63, quad = lane >> 4, l16 = lane & 15;
    int mbase = blockIdx.x * 64;

    // ---- phase-0 staging: A slots (8 DMAs/wave) + B half 0 (8 DMAs/wave) ----
    #pragma unroll
    for (int i = 0; i < 8; ++i) {            // A: slot BSLOTS + a, a in [0,32)
        int a = wave * 8 + i;
        const _Float16* M = A0h;
        int rem = a;
        if (MODE == 0 && a >= 4 * KI) { M = A1h; rem = a - 4 * KI; }
        int mt = rem / KI, kt = rem % KI;
        int rowb = mbase + mt * 16;
        int row = (rowb < N_NODES) ? (rowb + l16) : l16;   // clamp invalid tile
        dma16(lds + (BSLOTS + a) * 1024 + lane * 16,
              M + (size_t)row * K + kt * 32 + quad * 8);
    }
    #pragma unroll
    for (int i = 0; i < 8; ++i) {            // B half 0: slots 0..31
        int s = wave * 8 + i;
        int nb = s / KI, kt = s % KI;
        dma16(lds + s * 1024 + lane * 16,
              Bt + (size_t)(nb * 16 + l16) * K + kt * 32 + quad * 8);
    }

    // ---- prologue constants (overlap DMA drain) ----
    f16x8 scv[KI], shv[KI];
    if (MODE == 1 || APPLY_BN) {
        #pragma unroll
        for (int kt = 0; kt < KI; ++kt) {
            scv[kt] = *(const f16x8*)(scale16 + kt * 32 + quad * 8);
            shv[kt] = *(const f16x8*)(shift16 + kt * 32 + quad * 8);
        }
    }
    f16x8 evv;
    {
        _Float16 ev = (MODE == 0) ? (_Float16)(1.0f + epsArr[layer]) : (_Float16)0;
        #pragma unroll
        for (int j = 0; j < 8; ++j) evv[j] = ev;
    }

    __syncthreads();   // DMA drain (vmcnt) + barrier

    int mtile = mbase + wave * 16;
    bool valid = (mtile < N_NODES);    // 50000 % 16 == 0

    // ---- build A-fragments ONCE in registers (reused for both halves) ----
    f16x8 afrag[KI];
    #pragma unroll
    for (int kt = 0; kt < KI; ++kt) {
        f16x8 x = *(const f16x8*)(lds + (BSLOTS + wave * KI + kt) * 1024 + lane * 16);
        if (MODE == 0) {
            f16x8 y = *(const f16x8*)(lds + (BSLOTS + 4 * KI + wave * KI + kt) * 1024 + lane * 16);
            if (APPLY_BN) x = relu8(x * scv[kt] + shv[kt]);
            afrag[kt] = evv * x + y;
        } else {
            afrag[kt] = relu8(x * scv[kt] + shv[kt]);
        }
    }

    #pragma unroll
    for (int half = 0; half < 2; ++half) {
        if (half == 1) {
            __syncthreads();   // B0 reads + stats-combine reads done
            #pragma unroll
            for (int i = 0; i < 8; ++i) {    // B half 1 over slots 0..31
                int s = wave * 8 + i;
                int nb = s / KI, kt = s % KI;
                dma16(lds + s * 1024 + lane * 16,
                      Bt + (size_t)(HC + nb * 16 + l16) * K + kt * 32 + quad * 8);
            }
            __syncthreads();   // drain
        }
        int nbase = half * HC;

        f32x4 acc[NT];
        #pragma unroll
        for (int nt = 0; nt < NT; ++nt) acc[nt] = (f32x4){0, 0, 0, 0};

        #pragma unroll
        for (int kt = 0; kt < KI; ++kt) {
            #pragma unroll
            for (int nt = 0; nt < NT; ++nt) {
                f16x8 b = *(const f16x8*)(lds + (nt * KI + kt) * 1024 + lane * 16);
                acc[nt] = __builtin_amdgcn_mfma_f32_16x16x32_f16(afrag[kt], b, acc[nt], 0, 0, 0);
            }
        }

        // ---- epilogue (C layout: col=l16, row=quad*4+r) ----
        float s_acc[NT], q_acc[NT];
        #pragma unroll
        for (int nt = 0; nt < NT; ++nt) {
            int c = nbase + nt * 16 + l16;
            float s = 0.f, q = 0.f;
            if (valid) {
                float bv = bias[c];
                float v[4];
                #pragma unroll
                for (int r = 0; r < 4; ++r) v[r] = acc[nt][r] + bv;
                #pragma unroll
                for (int r = 0; r < 4; ++r)
                    Cout[(size_t)(mtile + quad * 4 + r) * NC + c] = (_Float16)v[r];
                if (STATS) {
                    s = v[0] + v[1] + v[2] + v[3];
                    q = v[0]*v[0] + v[1]*v[1] + v[2]*v[2] + v[3]*v[3];
                }
            }
            s_acc[nt] = s; q_acc[nt] = q;
        }

        if (STATS) {
            __syncthreads();   // all MFMA reads of B-half done; reuse LDS for combine
            float* fs = (float*)lds;
            float* fq = fs + 2048;
            #pragma unroll
            for (int nt = 0; nt < NT; ++nt) {
                float s = s_acc[nt], q = q_acc[nt];
                s += __shfl_xor(s, 16, 64); s += __shfl_xor(s, 32, 64);
                q += __shfl_xor(q, 16, 64); q += __shfl_xor(q, 32, 64);
                if (lane < 16) {
                    fs[wave * HC + nt * 16 + l16] = s;
                    fq[wave * HC + nt * 16 + l16] = q;
                }
            }
            __syncthreads();
            for (int c = tid; c < HC; c += 256) {
                float s = fs[c] + fs[HC + c] + fs[2 * HC + c] + fs[3 * HC + c];
                float q = fq[c] + fq[HC + c] + fq[2 * HC + c] + fq[3 * HC + c];
                psum[(size_t)blockIdx.x * NC + nbase + c] = s;
                psq [(size_t)blockIdx.x * NC + nbase + c] = q;
            }
        }
    }
}

// ---- per-column partial reduce + BN finalize (C blocks x 64 threads) ----
template <int C, int PARTS>
__global__ void bn_reduce_finalize(const float* __restrict__ psum, const float* __restrict__ psq,
                                   const float* __restrict__ g, const float* __restrict__ b,
                                   _Float16* __restrict__ scale16, _Float16* __restrict__ shift16) {
    int c = blockIdx.x;
    int t = threadIdx.x;
    float s = 0.f, q = 0.f;
    for (int bb = t; bb < PARTS; bb += 64) {
        s += psum[(size_t)bb * C + c];
        q += psq [(size_t)bb * C + c];
    }
    #pragma unroll
    for (int off = 32; off >= 1; off >>= 1) {
        s += __shfl_xor(s, off, 64);
        q += __shfl_xor(q, off, 64);
    }
    if (t == 0) {
        float mean = s * (1.0f / N_NODES);
        float var = q * (1.0f / N_NODES) - mean * mean;
        float sc = g[c] * rsqrtf(var + 1e-5f);
        scale16[c] = (_Float16)sc;
        shift16[c] = (_Float16)(b[c] - mean * sc);
    }
}

// ---------------- pooling ----------------
__global__ void count_graph(const int* __restrict__ batch, int* __restrict__ gcnt) {
    int n = blockIdx.x * 256 + threadIdx.x;
    if (n < N_NODES) atomicAdd(&gcnt[batch[n]], 1);
}

__global__ void scan_g(const int* __restrict__ gcnt, int* __restrict__ gptr) {
    __shared__ int s[512];
    int v = gcnt[threadIdx.x];
    s[threadIdx.x] = v;
    __syncthreads();
    for (int off = 1; off < 512; off <<= 1) {
        int t = (threadIdx.x >= off) ? s[threadIdx.x - off] : 0;
        __syncthreads();
        s[threadIdx.x] += t;
        __syncthreads();
    }
    gptr[threadIdx.x] = s[threadIdx.x] - v;
    if (threadIdx.x == 511) gptr[512] = s[511];
}

// pool + output head fused: block per graph
__global__ void pool_out(const _Float16* __restrict__ h, const int* __restrict__ gptr,
                         const float* __restrict__ Wout, const float* __restrict__ bout,
                         float* __restrict__ out) {
    __shared__ float red[4][128];
    __shared__ float hgrow[128];
    int g = blockIdx.x;
    int wave = threadIdx.x >> 6, lane = threadIdx.x & 63;
    int n0 = gptr[g], n1 = gptr[g + 1];
    float2 acc = {0.f, 0.f};
    for (int n = n0 + wave; n < n1; n += 4) {
        f16x2 v = ((const f16x2*)(h + (size_t)n * DIM))[lane];
        acc.x += (float)v[0]; acc.y += (float)v[1];
    }
    red[wave][lane * 2] = acc.x;
    red[wave][lane * 2 + 1] = acc.y;
    __syncthreads();
    if (wave == 0) {
        float tx = red[0][lane*2]   + red[1][lane*2]   + red[2][lane*2]   + red[3][lane*2];
        float ty = red[0][lane*2+1] + red[1][lane*2+1] + red[2][lane*2+1] + red[3][lane*2+1];
        float inv = 1.0f / fmaxf((float)(n1 - n0), 1.0f);
        hgrow[lane * 2] = tx * inv;
        hgrow[lane * 2 + 1] = ty * inv;
    }
    __syncthreads();
    int t = threadIdx.x;
    if (t < TDIM) {
        float acc2 = bout[t];
        for (int d = 0; d < DIM; ++d) acc2 += hgrow[d] * Wout[d * TDIM + t];
        out[g * TDIM + t] = acc2;
    }
}

extern "C" void kernel_launch(void* const* d_in, const int* in_sizes, int n_in,
                              void* d_out, int out_size, void* d_ws, size_t ws_size,
                              hipStream_t stream) {
    const int*   x     = (const int*)d_in[0];
    const int*   ei    = (const int*)d_in[1];
    const int*   batch = (const int*)d_in[2];
    const float* emb   = (const float*)d_in[3];
    const float* W1    = (const float*)d_in[4];
    const float* b1    = (const float*)d_in[5];
    const float* g1    = (const float*)d_in[6];
    const float* be1   = (const float*)d_in[7];
    const float* W2    = (const float*)d_in[8];
    const float* b2    = (const float*)d_in[9];
    const float* epsA  = (const float*)d_in[10];
    const float* bng   = (const float*)d_in[11];
    const float* bnb   = (const float*)d_in[12];
    const float* Wout  = (const float*)d_in[13];
    const float* bout  = (const float*)d_in[14];
    float* out = (float*)d_out;

    const int* srcIdx = ei;
    const int* dstIdx = ei + N_EDGES;

    char* base = (char*)d_ws;
    size_t off = 0;
    auto alloc = [&](size_t bytes) {
        char* p = base + off;
        off = (off + bytes + 255) & ~(size_t)255;
        return p;
    };
    _Float16* hraw  = (_Float16*)alloc((size_t)N_NODES * DIM * 2);
    _Float16* hrel  = (_Float16*)alloc((size_t)N_NODES * DIM * 2);   // layer-0 gather input
    _Float16* agg   = (_Float16*)alloc((size_t)N_NODES * DIM * 2);
    _Float16* z16   = (_Float16*)alloc((size_t)N_NODES * DIM2 * 2);
    _Float16* h2    = (_Float16*)alloc((size_t)N_NODES * DIM * 2);
    _Float16* W1t   = (_Float16*)alloc((size_t)NLAYER * DIM * DIM2 * 2);
    _Float16* W2t   = (_Float16*)alloc((size_t)NLAYER * DIM * DIM2 * 2);
    int*   rp    = (int*)alloc((N_NODES + 1) * 4);
    int*   tmpN  = (int*)alloc(N_NODES * 4);     // deg, then countdown cursor
    int*   col   = (int*)alloc(N_EDGES * 4);
    int*   bsum  = (int*)alloc(128 * 4);
    int*   boff  = (int*)alloc(128 * 4);
    int*   gcnt  = (int*)alloc(NGRAPH * 4);
    int*   gptr  = (int*)alloc((NGRAPH + 1) * 4);
    float* psumA = (float*)alloc((size_t)ROWGRPS * DIM2 * 4);
    float* psqA  = (float*)alloc((size_t)ROWGRPS * DIM2 * 4);
    float* psumB = (float*)alloc((size_t)ROWGRPS * DIM * 4);
    float* psqB  = (float*)alloc((size_t)ROWGRPS * DIM * 4);
    _Float16* scl1h = (_Float16*)alloc(DIM2 * 2);
    _Float16* sft1h = (_Float16*)alloc(DIM2 * 2);
    _Float16* scl2h = (_Float16*)alloc(DIM * 2);
    _Float16* sft2h = (_Float16*)alloc(DIM * 2);

    convert_w<<<(NLAYER * DIM * DIM2 + 255) / 256, 256, 0, stream>>>(W1, W2, W1t, W2t);
    atom_encoder<<<N_NODES / 4, 256, 0, stream>>>(x, emb, hraw, hrel);

    // CSR build (reused by all 5 layers). Cursor = deg via atomicSub (no 2nd memset).
    hipMemsetAsync(tmpN, 0, N_NODES * 4, stream);
    count_deg<<<(N_EDGES + 255) / 256, 256, 0, stream>>>(dstIdx, tmpN);
    scan_a<<<98, 512, 0, stream>>>(tmpN, rp, bsum);
    scan_b<<<1, 128, 0, stream>>>(bsum, boff);
    scan_c<<<98, 512, 0, stream>>>(rp, boff);
    {
        const int step = N_NODES / CSR_PASSES;   // 12500
        for (int p = 0; p < CSR_PASSES; ++p) {
            int lo = p * step;
            int hi = (p == CSR_PASSES - 1) ? N_NODES : lo + step;
            fill_csr_range<<<(N_EDGES + 255) / 256, 256, 0, stream>>>(
                srcIdx, dstIdx, rp, tmpN, col, lo, hi);
        }
    }

    // graph pooling CSR
    hipMemsetAsync(gcnt, 0, NGRAPH * 4, stream);
    count_graph<<<(N_NODES + 255) / 256, 256, 0, stream>>>(batch, gcnt);
    scan_g<<<1, 512, 0, stream>>>(gcnt, gptr);

    for (int i = 0; i < NLAYER; ++i) {
        if (i == 0)
            gather_agg<0><<<(N_NODES + 3) / 4, 256, 0, stream>>>(hrel, rp, col, nullptr, nullptr, agg);
        else
            gather_agg<1><<<(N_NODES + 3) / 4, 256, 0, stream>>>(h2, rp, col, scl2h, sft2h, agg);

        if (i == 0)
            gemm_mfma<128, 256, 0, 0, 1><<<ROWGRPS, 256, 0, stream>>>(
                hraw, agg, W1t, b1, nullptr, nullptr, epsA, 0, z16, psumA, psqA);
        else
            gemm_mfma<128, 256, 0, 1, 1><<<ROWGRPS, 256, 0, stream>>>(
                h2, agg, W1t + (size_t)i * DIM * DIM2, b1 + i * 256,
                scl2h, sft2h, epsA, i, z16, psumA, psqA);

        bn_reduce_finalize<256, ROWGRPS><<<DIM2, 64, 0, stream>>>(
            psumA, psqA, g1 + i * 256, be1 + i * 256, scl1h, sft1h);

        if (i < NLAYER - 1) {
            gemm_mfma<256, 128, 1, 0, 1><<<ROWGRPS, 256, 0, stream>>>(
                z16, nullptr, W2t + (size_t)i * DIM * DIM2, b2 + i * 128,
                scl1h, sft1h, epsA, i, h2, psumB, psqB);
            bn_reduce_finalize<128, ROWGRPS><<<DIM, 64, 0, stream>>>(
                psumB, psqB, bng + i * 128, bnb + i * 128, scl2h, sft2h);
        } else {
            gemm_mfma<256, 128, 1, 0, 0><<<ROWGRPS, 256, 0, stream>>>(
                z16, nullptr, W2t + (size_t)i * DIM * DIM2, b2 + i * 128,
                scl1h, sft1h, epsA, i, h2, psumB, psqB);
        }
    }

    pool_out<<<NGRAPH, 256, 0, stream>>>(h2, gptr, Wout, bout, out);
}

// Round 18
// 715.708 us; speedup vs baseline: 1.0792x; 1.0792x over previous
//
#include <hip/hip_runtime.h>
#include <hip/hip_bf16.h>

#define N_NODES 50000
#define N_EDGES 800000
#define DIM     128
#define DIM2    256
#define NLAYER  5
#define NGRAPH  512
#define TDIM    10
#define VMAX    119
#define ROWGRPS 782            // 782 row-groups x 64 rows = 50048 >= 50000
#define CSR_PASSES 4

typedef _Float16 f16x8 __attribute__((ext_vector_type(8)));
typedef _Float16 f16x2 __attribute__((ext_vector_type(2)));
typedef float    f32x4 __attribute__((ext_vector_type(4)));

// async global->LDS DMA, 16 B/lane; no dest VGPR so the scheduler CANNOT sink it.
static __device__ inline void dma16(void* lds, const void* g) {
#if defined(__has_builtin) && __has_builtin(__builtin_amdgcn_global_load_lds)
    __builtin_amdgcn_global_load_lds(
        (const __attribute__((address_space(1))) unsigned int*)g,
        (__attribute__((address_space(3))) unsigned int*)lds,
        16, 0, 0);
#else
    *(f16x8*)lds = *(const f16x8*)g;   // sync fallback, same layout
#endif
}

static __device__ inline f16x8 relu8(f16x8 v) {
#if __has_builtin(__builtin_elementwise_max)
    return __builtin_elementwise_max(v, (f16x8){0, 0, 0, 0, 0, 0, 0, 0});
#else
    #pragma unroll
    for (int j = 0; j < 8; ++j) v[j] = v[j] > (_Float16)0 ? v[j] : (_Float16)0;
    return v;
#endif
}

static __device__ inline f16x2 relu2(f16x2 v) {
#if __has_builtin(__builtin_elementwise_max)
    return __builtin_elementwise_max(v, (f16x2){0, 0});
#else
    #pragma unroll
    for (int j = 0; j < 2; ++j) v[j] = v[j] > (_Float16)0 ? v[j] : (_Float16)0;
    return v;
#endif
}

// ---------------- weight convert + transpose to f16 [n][k] ----------------
__global__ void convert_w(const float* __restrict__ W1, const float* __restrict__ W2,
                          _Float16* __restrict__ W1t, _Float16* __restrict__ W2t) {
    int idx = blockIdx.x * 256 + threadIdx.x;
    if (idx >= NLAYER * DIM * DIM2) return;
    int l = idx / (DIM * DIM2);
    int rem = idx % (DIM * DIM2);
    int k1 = rem / DIM2, n1 = rem % DIM2;
    W1t[(size_t)l * DIM * DIM2 + (size_t)n1 * DIM + k1] = (_Float16)W1[idx];
    int k2 = rem / DIM, n2 = rem % DIM;
    W2t[(size_t)l * DIM * DIM2 + (size_t)n2 * DIM2 + k2] = (_Float16)W2[idx];
}

// ---------------- atom encoder -> hraw f16 (GEMM1 layer0 A), hrel f16 (layer0 gather) ---
__global__ void atom_encoder(const int* __restrict__ x, const float* __restrict__ emb,
                             _Float16* __restrict__ hraw, _Float16* __restrict__ hrelu) {
    int node = blockIdx.x * 4 + (threadIdx.x >> 6);
    int lane = threadIdx.x & 63;
    if (node >= N_NODES) return;
    float2 acc = {0.f, 0.f};
    const int* xr = x + node * 9;
    #pragma unroll
    for (int t = 0; t < 9; ++t) {
        int v = xr[t];
        const float2* row = (const float2*)(emb + ((size_t)t * VMAX + v) * DIM);
        float2 e = row[lane];
        acc.x += e.x; acc.y += e.y;
    }
    f16x2 o, orl;
    o[0] = (_Float16)acc.x; o[1] = (_Float16)acc.y;
    orl[0] = (_Float16)fmaxf(acc.x, 0.f); orl[1] = (_Float16)fmaxf(acc.y, 0.f);
    ((f16x2*)(hraw + (size_t)node * DIM))[lane] = o;
    ((f16x2*)(hrelu + (size_t)node * DIM))[lane] = orl;
}

// ---------------- CSR build ----------------
__global__ void count_deg(const int* __restrict__ dst, int* __restrict__ deg) {
    int e = blockIdx.x * blockDim.x + threadIdx.x;
    if (e < N_EDGES) atomicAdd(&deg[dst[e]], 1);
}

__global__ void scan_a(const int* __restrict__ deg, int* __restrict__ rp, int* __restrict__ bsum) {
    __shared__ int s[512];
    int i = blockIdx.x * 512 + threadIdx.x;
    int v = (i < N_NODES) ? deg[i] : 0;
    s[threadIdx.x] = v;
    __syncthreads();
    for (int off = 1; off < 512; off <<= 1) {
        int t = (threadIdx.x >= off) ? s[threadIdx.x - off] : 0;
        __syncthreads();
        s[threadIdx.x] += t;
        __syncthreads();
    }
    if (i < N_NODES) rp[i] = s[threadIdx.x] - v;   // exclusive
    if (threadIdx.x == 511) bsum[blockIdx.x] = s[511];
}

__global__ void scan_b(const int* __restrict__ bsum, int* __restrict__ boff) {
    __shared__ int s[128];
    const int NB = 98;
    int v = (threadIdx.x < NB) ? bsum[threadIdx.x] : 0;
    s[threadIdx.x] = v;
    __syncthreads();
    for (int off = 1; off < 128; off <<= 1) {
        int t = (threadIdx.x >= off) ? s[threadIdx.x - off] : 0;
        __syncthreads();
        s[threadIdx.x] += t;
        __syncthreads();
    }
    if (threadIdx.x < NB) boff[threadIdx.x] = s[threadIdx.x] - v;
}

__global__ void scan_c(int* __restrict__ rp, const int* __restrict__ boff) {
    int i = blockIdx.x * 512 + threadIdx.x;
    if (i < N_NODES) rp[i] += boff[blockIdx.x];
    if (blockIdx.x == 0 && threadIdx.x == 0) rp[N_NODES] = N_EDGES;
}

// fill CSR for one dst range (L2-resident col footprint per pass -> write-combining).
__global__ void fill_csr_range(const int* __restrict__ src, const int* __restrict__ dst,
                               const int* __restrict__ rp, int* __restrict__ cursor,
                               int* __restrict__ col, int lo, int hi) {
    int e = blockIdx.x * blockDim.x + threadIdx.x;
    if (e >= N_EDGES) return;
    int d = dst[e];
    if (d < lo || d >= hi) return;
    int pos = atomicSub(&cursor[d], 1) - 1;
    col[rp[d] + pos] = src[e];
}

// -------- aggregation, unroll 16/8/4 tiers (round-16 proven best for this pattern) ----
template <int APPLY_BN>
__global__ void gather_agg(const _Float16* __restrict__ hsrc, const int* __restrict__ rp,
                           const int* __restrict__ col, const _Float16* __restrict__ scale16,
                           const _Float16* __restrict__ shift16, _Float16* __restrict__ agg) {
    int node = blockIdx.x * 4 + (threadIdx.x >> 6);
    int lane = threadIdx.x & 63;
    if (node >= N_NODES) return;
    f16x2 sc = {0, 0}, sh = {0, 0};
    if (APPLY_BN) {
        sc = ((const f16x2*)scale16)[lane];
        sh = ((const f16x2*)shift16)[lane];
    }
    int e0 = rp[node], e1 = rp[node + 1];
    float2 acc = {0.f, 0.f};
    int e = e0;
    for (; e + 16 <= e1; e += 16) {
        int idx[16];
        #pragma unroll
        for (int j = 0; j < 16; ++j) idx[j] = col[e + j];
        f16x2 v[16];
        #pragma unroll
        for (int j = 0; j < 16; ++j)
            v[j] = ((const f16x2*)(hsrc + (size_t)idx[j] * DIM))[lane];
        #pragma unroll
        for (int j = 0; j < 16; ++j) {
            f16x2 w = v[j];
            if (APPLY_BN) w = relu2(w * sc + sh);
            acc.x += (float)w[0]; acc.y += (float)w[1];
        }
    }
    for (; e + 8 <= e1; e += 8) {
        int idx[8];
        #pragma unroll
        for (int j = 0; j < 8; ++j) idx[j] = col[e + j];
        f16x2 v[8];
        #pragma unroll
        for (int j = 0; j < 8; ++j)
            v[j] = ((const f16x2*)(hsrc + (size_t)idx[j] * DIM))[lane];
        #pragma unroll
        for (int j = 0; j < 8; ++j) {
            f16x2 w = v[j];
            if (APPLY_BN) w = relu2(w * sc + sh);
            acc.x += (float)w[0]; acc.y += (float)w[1];
        }
    }
    for (; e + 4 <= e1; e += 4) {
        int idx[4];
        #pragma unroll
        for (int j = 0; j < 4; ++j) idx[j] = col[e + j];
        f16x2 v[4];
        #pragma unroll
        for (int j = 0; j < 4; ++j)
            v[j] = ((const f16x2*)(hsrc + (size_t)idx[j] * DIM))[lane];
        #pragma unroll
        for (int j = 0; j < 4; ++j) {
            f16x2 w = v[j];
            if (APPLY_BN) w = relu2(w * sc + sh);
            acc.x += (float)w[0]; acc.y += (float)w[1];
        }
    }
    for (; e < e1; ++e) {
        f16x2 w = ((const f16x2*)(hsrc + (size_t)col[e] * DIM))[lane];
        if (APPLY_BN) w = relu2(w * sc + sh);
        acc.x += (float)w[0]; acc.y += (float)w[1];
    }
    f16x2 o;
    o[0] = (_Float16)acc.x; o[1] = (_Float16)acc.y;
    ((f16x2*)(agg + (size_t)node * DIM))[lane] = o;
}

// ---------------- MFMA GEMM: DMA-staged, A staged ONCE + both column halves -----------
// (round-16 proven) Grid = ROWGRPS; block = 64 rows x all NC cols in two half-phases.
// 64 LDS slots x 1 KB: 0..31 = B-half frags, 32..63 = A frags. A-frags built once in
// registers and reused across halves. Stats via LDS combine, no atomics.
// MODE 0: A[m][k] = (1+eps) * f(A0[m][k]) + A1[m][k], f = relu(x*sc+sh) if APPLY_BN
// MODE 1: A[m][k] = relu(A0[m][k]*sc[k] + sh[k])
template <int K, int NC, int MODE, int APPLY_BN, int STATS>
__global__ __launch_bounds__(256, 2) void gemm_mfma(
    const _Float16* __restrict__ A0h, const _Float16* __restrict__ A1h,
    const _Float16* __restrict__ Bt, const float* __restrict__ bias,
    const _Float16* __restrict__ scale16, const _Float16* __restrict__ shift16,
    const float* __restrict__ epsArr, int layer, _Float16* __restrict__ Cout,
    float* __restrict__ psum, float* __restrict__ psq) {
    const int HC = NC / 2;        // cols per half (128 or 64)
    const int NT = HC / 16;       // n-tiles per half (8 or 4)
    const int KI = K / 32;        // k-steps (4 or 8)
    const int BSLOTS = NT * KI;   // 32 for both shapes
    __shared__ __align__(16) char lds[65536];   // 64 slots x 1 KB

    int tid = threadIdx.x;
    int wave = tid >> 6, lane = tid & 63, quad = lane >> 4, l16 = lane & 15;
    int mbase = blockIdx.x * 64;

    // ---- phase-0 staging: A slots (8 DMAs/wave) + B half 0 (8 DMAs/wave) ----
    #pragma unroll
    for (int i = 0; i < 8; ++i) {            // A: slot BSLOTS + a, a in [0,32)
        int a = wave * 8 + i;
        const _Float16* M = A0h;
        int rem = a;
        if (MODE == 0 && a >= 4 * KI) { M = A1h; rem = a - 4 * KI; }
        int mt = rem / KI, kt = rem % KI;
        int rowb = mbase + mt * 16;
        int row = (rowb < N_NODES) ? (rowb + l16) : l16;   // clamp invalid tile
        dma16(lds + (BSLOTS + a) * 1024 + lane * 16,
              M + (size_t)row * K + kt * 32 + quad * 8);
    }
    #pragma unroll
    for (int i = 0; i < 8; ++i) {            // B half 0: slots 0..31
        int s = wave * 8 + i;
        int nb = s / KI, kt = s % KI;
        dma16(lds + s * 1024 + lane * 16,
              Bt + (size_t)(nb * 16 + l16) * K + kt * 32 + quad * 8);
    }

    // ---- prologue constants (overlap DMA drain) ----
    f16x8 scv[KI], shv[KI];
    if (MODE == 1 || APPLY_BN) {
        #pragma unroll
        for (int kt = 0; kt < KI; ++kt) {
            scv[kt] = *(const f16x8*)(scale16 + kt * 32 + quad * 8);
            shv[kt] = *(const f16x8*)(shift16 + kt * 32 + quad * 8);
        }
    }
    f16x8 evv;
    {
        _Float16 ev = (MODE == 0) ? (_Float16)(1.0f + epsArr[layer]) : (_Float16)0;
        #pragma unroll
        for (int j = 0; j < 8; ++j) evv[j] = ev;
    }

    __syncthreads();   // DMA drain (vmcnt) + barrier

    int mtile = mbase + wave * 16;
    bool valid = (mtile < N_NODES);    // 50000 % 16 == 0

    // ---- build A-fragments ONCE in registers (reused for both halves) ----
    f16x8 afrag[KI];
    #pragma unroll
    for (int kt = 0; kt < KI; ++kt) {
        f16x8 x = *(const f16x8*)(lds + (BSLOTS + wave * KI + kt) * 1024 + lane * 16);
        if (MODE == 0) {
            f16x8 y = *(const f16x8*)(lds + (BSLOTS + 4 * KI + wave * KI + kt) * 1024 + lane * 16);
            if (APPLY_BN) x = relu8(x * scv[kt] + shv[kt]);
            afrag[kt] = evv * x + y;
        } else {
            afrag[kt] = relu8(x * scv[kt] + shv[kt]);
        }
    }

    #pragma unroll
    for (int half = 0; half < 2; ++half) {
        if (half == 1) {
            __syncthreads();   // B0 reads + stats-combine reads done
            #pragma unroll
            for (int i = 0; i < 8; ++i) {    // B half 1 over slots 0..31
                int s = wave * 8 + i;
                int nb = s / KI, kt = s % KI;
                dma16(lds + s * 1024 + lane * 16,
                      Bt + (size_t)(HC + nb * 16 + l16) * K + kt * 32 + quad * 8);
            }
            __syncthreads();   // drain
        }
        int nbase = half * HC;

        f32x4 acc[NT];
        #pragma unroll
        for (int nt = 0; nt < NT; ++nt) acc[nt] = (f32x4){0, 0, 0, 0};

        #pragma unroll
        for (int kt = 0; kt < KI; ++kt) {
            #pragma unroll
            for (int nt = 0; nt < NT; ++nt) {
                f16x8 b = *(const f16x8*)(lds + (nt * KI + kt) * 1024 + lane * 16);
                acc[nt] = __builtin_amdgcn_mfma_f32_16x16x32_f16(afrag[kt], b, acc[nt], 0, 0, 0);
            }
        }

        // ---- epilogue (C layout: col=l16, row=quad*4+r) ----
        float s_acc[NT], q_acc[NT];
        #pragma unroll
        for (int nt = 0; nt < NT; ++nt) {
            int c = nbase + nt * 16 + l16;
            float s = 0.f, q = 0.f;
            if (valid) {
                float bv = bias[c];
                float v[4];
                #pragma unroll
                for (int r = 0; r < 4; ++r) v[r] = acc[nt][r] + bv;
                #pragma unroll
                for (int r = 0; r < 4; ++r)
                    Cout[(size_t)(mtile + quad * 4 + r) * NC + c] = (_Float16)v[r];
                if (STATS) {
                    s = v[0] + v[1] + v[2] + v[3];
                    q = v[0]*v[0] + v[1]*v[1] + v[2]*v[2] + v[3]*v[3];
                }
            }
            s_acc[nt] = s; q_acc[nt] = q;
        }

        if (STATS) {
            __syncthreads();   // all MFMA reads of B-half done; reuse LDS for combine
            float* fs = (float*)lds;
            float* fq = fs + 2048;
            #pragma unroll
            for (int nt = 0; nt < NT; ++nt) {
                float s = s_acc[nt], q = q_acc[nt];
                s += __shfl_xor(s, 16, 64); s += __shfl_xor(s, 32, 64);
                q += __shfl_xor(q, 16, 64); q += __shfl_xor(q, 32, 64);
                if (lane < 16) {
                    fs[wave * HC + nt * 16 + l16] = s;
                    fq[wave * HC + nt * 16 + l16] = q;
                }
            }
            __syncthreads();
            for (int c = tid; c < HC; c += 256) {
                float s = fs[c] + fs[HC + c] + fs[2 * HC + c] + fs[3 * HC + c];
                float q = fq[c] + fq[HC + c] + fq[2 * HC + c] + fq[3 * HC + c];
                psum[(size_t)blockIdx.x * NC + nbase + c] = s;
                psq [(size_t)blockIdx.x * NC + nbase + c] = q;
            }
        }
    }
}

// ---- per-column partial reduce + BN finalize (C blocks x 64 threads) ----
template <int C, int PARTS>
__global__ void bn_reduce_finalize(const float* __restrict__ psum, const float* __restrict__ psq,
                                   const float* __restrict__ g, const float* __restrict__ b,
                                   _Float16* __restrict__ scale16, _Float16* __restrict__ shift16) {
    int c = blockIdx.x;
    int t = threadIdx.x;
    float s = 0.f, q = 0.f;
    for (int bb = t; bb < PARTS; bb += 64) {
        s += psum[(size_t)bb * C + c];
        q += psq [(size_t)bb * C + c];
    }
    #pragma unroll
    for (int off = 32; off >= 1; off >>= 1) {
        s += __shfl_xor(s, off, 64);
        q += __shfl_xor(q, off, 64);
    }
    if (t == 0) {
        float mean = s * (1.0f / N_NODES);
        float var = q * (1.0f / N_NODES) - mean * mean;
        float sc = g[c] * rsqrtf(var + 1e-5f);
        scale16[c] = (_Float16)sc;
        shift16[c] = (_Float16)(b[c] - mean * sc);
    }
}

// ---------------- pooling ----------------
__global__ void count_graph(const int* __restrict__ batch, int* __restrict__ gcnt) {
    int n = blockIdx.x * 256 + threadIdx.x;
    if (n < N_NODES) atomicAdd(&gcnt[batch[n]], 1);
}

__global__ void scan_g(const int* __restrict__ gcnt, int* __restrict__ gptr) {
    __shared__ int s[512];
    int v = gcnt[threadIdx.x];
    s[threadIdx.x] = v;
    __syncthreads();
    for (int off = 1; off < 512; off <<= 1) {
        int t = (threadIdx.x >= off) ? s[threadIdx.x - off] : 0;
        __syncthreads();
        s[threadIdx.x] += t;
        __syncthreads();
    }
    gptr[threadIdx.x] = s[threadIdx.x] - v;
    if (threadIdx.x == 511) gptr[512] = s[511];
}

// pool + output head fused: block per graph
__global__ void pool_out(const _Float16* __restrict__ h, const int* __restrict__ gptr,
                         const float* __restrict__ Wout, const float* __restrict__ bout,
                         float* __restrict__ out) {
    __shared__ float red[4][128];
    __shared__ float hgrow[128];
    int g = blockIdx.x;
    int wave = threadIdx.x >> 6, lane = threadIdx.x & 63;
    int n0 = gptr[g], n1 = gptr[g + 1];
    float2 acc = {0.f, 0.f};
    for (int n = n0 + wave; n < n1; n += 4) {
        f16x2 v = ((const f16x2*)(h + (size_t)n * DIM))[lane];
        acc.x += (float)v[0]; acc.y += (float)v[1];
    }
    red[wave][lane * 2] = acc.x;
    red[wave][lane * 2 + 1] = acc.y;
    __syncthreads();
    if (wave == 0) {
        float tx = red[0][lane*2]   + red[1][lane*2]   + red[2][lane*2]   + red[3][lane*2];
        float ty = red[0][lane*2+1] + red[1][lane*2+1] + red[2][lane*2+1] + red[3][lane*2+1];
        float inv = 1.0f / fmaxf((float)(n1 - n0), 1.0f);
        hgrow[lane * 2] = tx * inv;
        hgrow[lane * 2 + 1] = ty * inv;
    }
    __syncthreads();
    int t = threadIdx.x;
    if (t < TDIM) {
        float acc2 = bout[t];
        for (int d = 0; d < DIM; ++d) acc2 += hgrow[d] * Wout[d * TDIM + t];
        out[g * TDIM + t] = acc2;
    }
}

extern "C" void kernel_launch(void* const* d_in, const int* in_sizes, int n_in,
                              void* d_out, int out_size, void* d_ws, size_t ws_size,
                              hipStream_t stream) {
    const int*   x     = (const int*)d_in[0];
    const int*   ei    = (const int*)d_in[1];
    const int*   batch = (const int*)d_in[2];
    const float* emb   = (const float*)d_in[3];
    const float* W1    = (const float*)d_in[4];
    const float* b1    = (const float*)d_in[5];
    const float* g1    = (const float*)d_in[6];
    const float* be1   = (const float*)d_in[7];
    const float* W2    = (const float*)d_in[8];
    const float* b2    = (const float*)d_in[9];
    const float* epsA  = (const float*)d_in[10];
    const float* bng   = (const float*)d_in[11];
    const float* bnb   = (const float*)d_in[12];
    const float* Wout  = (const float*)d_in[13];
    const float* bout  = (const float*)d_in[14];
    float* out = (float*)d_out;

    const int* srcIdx = ei;
    const int* dstIdx = ei + N_EDGES;

    char* base = (char*)d_ws;
    size_t off = 0;
    auto alloc = [&](size_t bytes) {
        char* p = base + off;
        off = (off + bytes + 255) & ~(size_t)255;
        return p;
    };
    _Float16* hraw  = (_Float16*)alloc((size_t)N_NODES * DIM * 2);
    _Float16* hrel  = (_Float16*)alloc((size_t)N_NODES * DIM * 2);   // layer-0 gather input
    _Float16* agg   = (_Float16*)alloc((size_t)N_NODES * DIM * 2);
    _Float16* z16   = (_Float16*)alloc((size_t)N_NODES * DIM2 * 2);
    _Float16* h2    = (_Float16*)alloc((size_t)N_NODES * DIM * 2);
    _Float16* W1t   = (_Float16*)alloc((size_t)NLAYER * DIM * DIM2 * 2);
    _Float16* W2t   = (_Float16*)alloc((size_t)NLAYER * DIM * DIM2 * 2);
    int*   rp    = (int*)alloc((N_NODES + 1) * 4);
    int*   tmpN  = (int*)alloc(N_NODES * 4);     // deg, then countdown cursor
    int*   col   = (int*)alloc(N_EDGES * 4);
    int*   bsum  = (int*)alloc(128 * 4);
    int*   boff  = (int*)alloc(128 * 4);
    int*   gcnt  = (int*)alloc(NGRAPH * 4);
    int*   gptr  = (int*)alloc((NGRAPH + 1) * 4);
    float* psumA = (float*)alloc((size_t)ROWGRPS * DIM2 * 4);
    float* psqA  = (float*)alloc((size_t)ROWGRPS * DIM2 * 4);
    float* psumB = (float*)alloc((size_t)ROWGRPS * DIM * 4);
    float* psqB  = (float*)alloc((size_t)ROWGRPS * DIM * 4);
    _Float16* scl1h = (_Float16*)alloc(DIM2 * 2);
    _Float16* sft1h = (_Float16*)alloc(DIM2 * 2);
    _Float16* scl2h = (_Float16*)alloc(DIM * 2);
    _Float16* sft2h = (_Float16*)alloc(DIM * 2);

    convert_w<<<(NLAYER * DIM * DIM2 + 255) / 256, 256, 0, stream>>>(W1, W2, W1t, W2t);
    atom_encoder<<<N_NODES / 4, 256, 0, stream>>>(x, emb, hraw, hrel);

    // CSR build (reused by all 5 layers). Cursor = deg via atomicSub (no 2nd memset).
    hipMemsetAsync(tmpN, 0, N_NODES * 4, stream);
    count_deg<<<(N_EDGES + 255) / 256, 256, 0, stream>>>(dstIdx, tmpN);
    scan_a<<<98, 512, 0, stream>>>(tmpN, rp, bsum);
    scan_b<<<1, 128, 0, stream>>>(bsum, boff);
    scan_c<<<98, 512, 0, stream>>>(rp, boff);
    {
        const int step = N_NODES / CSR_PASSES;   // 12500
        for (int p = 0; p < CSR_PASSES; ++p) {
            int lo = p * step;
            int hi = (p == CSR_PASSES - 1) ? N_NODES : lo + step;
            fill_csr_range<<<(N_EDGES + 255) / 256, 256, 0, stream>>>(
                srcIdx, dstIdx, rp, tmpN, col, lo, hi);
        }
    }

    // graph pooling CSR
    hipMemsetAsync(gcnt, 0, NGRAPH * 4, stream);
    count_graph<<<(N_NODES + 255) / 256, 256, 0, stream>>>(batch, gcnt);
    scan_g<<<1, 512, 0, stream>>>(gcnt, gptr);

    for (int i = 0; i < NLAYER; ++i) {
        if (i == 0)
            gather_agg<0><<<(N_NODES + 3) / 4, 256, 0, stream>>>(hrel, rp, col, nullptr, nullptr, agg);
        else
            gather_agg<1><<<(N_NODES + 3) / 4, 256, 0, stream>>>(h2, rp, col, scl2h, sft2h, agg);

        if (i == 0)
            gemm_mfma<128, 256, 0, 0, 1><<<ROWGRPS, 256, 0, stream>>>(
                hraw, agg, W1t, b1, nullptr, nullptr, epsA, 0, z16, psumA, psqA);
        else
            gemm_mfma<128, 256, 0, 1, 1><<<ROWGRPS, 256, 0, stream>>>(
                h2, agg, W1t + (size_t)i * DIM * DIM2, b1 + i * 256,
                scl2h, sft2h, epsA, i, z16, psumA, psqA);

        bn_reduce_finalize<256, ROWGRPS><<<DIM2, 64, 0, stream>>>(
            psumA, psqA, g1 + i * 256, be1 + i * 256, scl1h, sft1h);

        if (i < NLAYER - 1) {
            gemm_mfma<256, 128, 1, 0, 1><<<ROWGRPS, 256, 0, stream>>>(
                z16, nullptr, W2t + (size_t)i * DIM * DIM2, b2 + i * 128,
                scl1h, sft1h, epsA, i, h2, psumB, psqB);
            bn_reduce_finalize<128, ROWGRPS><<<DIM, 64, 0, stream>>>(
                psumB, psqB, bng + i * 128, bnb + i * 128, scl2h, sft2h);
        } else {
            gemm_mfma<256, 128, 1, 0, 0><<<ROWGRPS, 256, 0, stream>>>(
                z16, nullptr, W2t + (size_t)i * DIM * DIM2, b2 + i * 128,
                scl1h, sft1h, epsA, i, h2, psumB, psqB);
        }
    }

    pool_out<<<NGRAPH, 256, 0, stream>>>(h2, gptr, Wout, bout, out);
}